// Round 3
// baseline (208.978 us; speedup 1.0000x reference)
//
#include <hip/hip_runtime.h>

// Problem constants: B=16384, D_in=512, H=512
#define M_ROWS 16384
#define N_COLS 1536   // 3*H
#define K_DIM  512
#define H_DIM  512
#define NT     8      // K_DIM / 64 K-tiles

typedef __attribute__((ext_vector_type(8))) short short8;   // 8 bf16 = 4 VGPRs
typedef __attribute__((ext_vector_type(16))) float f32x16;  // 32x32 MFMA acc

__device__ __forceinline__ unsigned short f2bf(float f) {
  unsigned u = __float_as_uint(f);
  u += 0x7fffu + ((u >> 16) & 1u);   // RNE
  return (unsigned short)(u >> 16);
}
__device__ __forceinline__ float bf2f(unsigned short h) {
  return __uint_as_float(((unsigned)h) << 16);
}
__device__ __forceinline__ unsigned cvt_pk_bf16(float lo, float hi) {
  unsigned r;
  asm("v_cvt_pk_bf16_f32 %0, %1, %2" : "=v"(r) : "v"(lo), "v"(hi));  // RNE, lo in [15:0]
  return r;
}

__device__ __forceinline__ void gload_lds16(const void* g, void* l) {
  __builtin_amdgcn_global_load_lds((const __attribute__((address_space(1))) void*)g,
                                   (__attribute__((address_space(3))) void*)l,
                                   16, 0, 0);
}

// ---------------- fp32 -> bf16 convert, W only (9.4 MB pass) ----------------
__global__ __launch_bounds__(256) void cvt_w(
    const float* __restrict__ Wi, const float* __restrict__ Wh,
    unsigned short* __restrict__ Wib, unsigned short* __restrict__ Whb) {
  int i = blockIdx.x * blockDim.x + threadIdx.x;   // grid exactly 393216 threads
  const float* s; unsigned short* d; int off;
  if (i < 196608) { s = Wi; d = Wib; off = i; }
  else            { s = Wh; d = Whb; off = i - 196608; }
  float4 f = ((const float4*)s)[off];
  ushort4 u;
  u.x = f2bf(f.x); u.y = f2bf(f.y); u.z = f2bf(f.z); u.w = f2bf(f.w);
  ((ushort4*)d)[off] = u;
}

// ---------------- GEMM (bf16 MFMA 32x32x16) + bias, permuted store ----------
// C[m][n] = sum_k A[m][k]*W[n][k] + bias[n].  blockIdx.z: 0=(x,Wi,bi,xt) 1=(hx,Wh,bh,ht)
// v4 = v3 (fused fp32->bf16 A-staging, B via global_load_lds dbuf) + XCD-locality
// swizzle: XCD c (= linear&7) runs m-panels {c, c+8, ...} with all 12 n-panels
// CONSECUTIVELY, so the fp32 A-tile (256 KB) is L2-resident across its 12 re-reads
// (live set per XCD ~2 MB A + 1.5 MB W < 4 MB L2). Fixes round-2's 160 MB FETCH.
//   A (x/hx fp32): 8x dwordx4 -> 16x v_cvt_pk_bf16_f32 -> 4x swizzled ds_write_b128
//   B (W bf16):    global_load_lds (linear dest, pre-swizzled source), double-buffered
// Next-tile A-regs + B-gload issue BEFORE the MFMA phase; tile-end barrier is a raw
// s_barrier (no vmcnt drain) so they stay in flight across it (depth-1 overlap).
// LDS XOR swizzle: 16B chunk c of row r stored at physical chunk c^(r&7).
// Store permutation within each aligned 64-col group: value for true col
// 32*j + c (c=lane&31, j=0..1) stored at slot 2c+j  -> finalize decode unchanged.
__global__ __launch_bounds__(256, 3) void gemm_bf16(
    const float* __restrict__ x, const float* __restrict__ hx,
    const unsigned short* __restrict__ Wib, const unsigned short* __restrict__ Whb,
    const float* __restrict__ b_i2h, const float* __restrict__ b_h2h,
    unsigned short* __restrict__ xt, unsigned short* __restrict__ ht) {
  const int mat = blockIdx.z;
  const float* A32         = mat ? hx : x;
  const unsigned short* Bw = mat ? Whb : Wib;
  const float* bias        = mat ? b_h2h : b_i2h;
  unsigned short* outp     = mat ? ht : xt;

  // XCD-locality decode: 1536 blocks/matrix. xcd = l&7; within an XCD the
  // serial order is n-panel fastest over m-panels {xcd, xcd+8, ...}.
  const int l  = blockIdx.x;
  const int q  = l >> 3, c = l & 7;
  const int mp = (q / 12) * 8 + c;      // m-panel in [0,128)
  const int np = q % 12;                // n-panel in [0,12)
  const int m0 = mp * 128;
  const int n0 = np * 128;

  // ldsA: [128][64] single (16 KiB). ldsB: 2 x [128][64] double (32 KiB). 48 KiB.
  __shared__ short lds[3 * 128 * 64];
  short* ldsA = lds;
  short* ldsB = lds + 128 * 64;

  const int t = threadIdx.x;
  const int w = t >> 6, lane = t & 63;
  const int w_row = w >> 1, w_col = w & 1;
  const int l31 = lane & 31, h = lane >> 5;
  const int srow = lane >> 3;                   // 0..7 row within 8-row seg
  const int scol = ((lane & 7) ^ srow) * 8;     // XOR pre-swizzled source chunk (B)

  // ---- A staging: per thread 4 chunks (rows w*32+s*8+(lane>>3), 32B group lane&7)
  const int arow_s = w * 32 + (lane >> 3);      // + s*8
  const int ag = lane & 7;
  float4 areg[8];
  auto issueA = [&](int kt) {
    const int k0 = kt * 64;
#pragma unroll
    for (int s = 0; s < 4; ++s) {
      const float* src = A32 + (size_t)(m0 + arow_s + s * 8) * K_DIM + k0 + ag * 8;
      areg[2 * s]     = *(const float4*)src;
      areg[2 * s + 1] = *(const float4*)(src + 4);
    }
  };
  auto issueB = [&](int kt) {
    short* sB = ldsB + (kt & 1) * 8192;
    const int k0 = kt * 64;
#pragma unroll
    for (int q2 = 0; q2 < 4; ++q2) {
      const int br = w * 32 + q2 * 8;
      gload_lds16(Bw + (size_t)(n0 + br + srow) * K_DIM + k0 + scol, &sB[br * 64]);
    }
  };
  auto writeA = [&]() {
#pragma unroll
    for (int s = 0; s < 4; ++s) {
      const int r = arow_s + s * 8;
      float4 f0 = areg[2 * s], f1 = areg[2 * s + 1];
      uint4 u;
      u.x = cvt_pk_bf16(f0.x, f0.y);
      u.y = cvt_pk_bf16(f0.z, f0.w);
      u.z = cvt_pk_bf16(f1.x, f1.y);
      u.w = cvt_pk_bf16(f1.z, f1.w);
      *(uint4*)&ldsA[r * 64 + ((ag ^ (r & 7)) * 8)] = u;
    }
  };

  f32x16 acc[2][2];
#pragma unroll
  for (int i = 0; i < 2; ++i)
#pragma unroll
    for (int j = 0; j < 2; ++j)
#pragma unroll
      for (int r = 0; r < 16; ++r) acc[i][j][r] = 0.f;

  issueA(0);
  issueB(0);

  for (int kt = 0; kt < NT; ++kt) {
    writeA();            // vmcnt waits on areg at use; converts + swizzled ds_write
    __syncthreads();     // drains vmcnt (B tile landed) + lgkmcnt (A writes visible)
    if (kt < NT - 1) {
      issueA(kt + 1);    // fp32 loads to regs: fly across the raw barrier
      issueB(kt + 1);    // gload_lds into the OTHER B buffer: safe during compute
    }
    const short* lB = ldsB + (kt & 1) * 8192;
#pragma unroll
    for (int kk = 0; kk < 4; ++kk) {
      // lane needs k = kk*16 + h*8 + j -> logical chunk kk*2+h,
      // physical chunk (kk*2+h) ^ (row&7), row&7 == l31&7 here.
      const int chunk = ((kk * 2 + h) ^ (l31 & 7)) * 8;
      short8 af[2], bfr[2];
#pragma unroll
      for (int i = 0; i < 2; ++i)
        af[i] = *(const short8*)&ldsA[(w_row * 64 + i * 32 + l31) * 64 + chunk];
#pragma unroll
      for (int j = 0; j < 2; ++j)
        bfr[j] = *(const short8*)&lB[(w_col * 64 + j * 32 + l31) * 64 + chunk];
      __builtin_amdgcn_s_setprio(1);
#pragma unroll
      for (int i = 0; i < 2; ++i)
#pragma unroll
        for (int j = 0; j < 2; ++j)
          acc[i][j] = __builtin_amdgcn_mfma_f32_32x32x16_bf16(af[i], bfr[j], acc[i][j], 0, 0, 0);
      __builtin_amdgcn_s_setprio(0);
    }
    if (kt < NT - 1) {
      // WAR on ldsA / ldsB-read-buffer. Raw barrier: do NOT drain vmcnt, so the
      // kt+1 loads issued above stay in flight (drained by next syncthreads).
      asm volatile("" ::: "memory");
      __builtin_amdgcn_s_barrier();
      asm volatile("" ::: "memory");
    }
  }

  // Epilogue: bias + packed permuted ushort2 store.
  // C/D: col=l31, row=(reg&3)+8*(reg>>2)+4*h
  const float biasj0 = bias[n0 + w_col * 64 + l31];
  const float biasj1 = bias[n0 + w_col * 64 + 32 + l31];
#pragma unroll
  for (int i = 0; i < 2; ++i) {
#pragma unroll
    for (int g = 0; g < 4; ++g) {
#pragma unroll
      for (int d = 0; d < 4; ++d) {
        const int reg = g * 4 + d;
        const int row = d + 8 * g + 4 * h;
        ushort2 pk;
        pk.x = f2bf(acc[i][0][reg] + biasj0);
        pk.y = f2bf(acc[i][1][reg] + biasj1);
        *(ushort2*)(outp + (size_t)(m0 + w_row * 64 + i * 32 + row) * N_COLS +
                    n0 + w_col * 64 + 2 * l31) = pk;
      }
    }
  }
}

// ---------------- finalize: wave-per-row, b128 loads, float4 hx/out ---------
// Permuted slot s (within aligned 64-group) holds true col 32*(s&1)+(s>>1).
// hx is read as fp32 directly (exact, no hxb buffer).
__global__ __launch_bounds__(256) void finalize_kernel(
    const unsigned short* __restrict__ xt, const unsigned short* __restrict__ ht,
    const float* __restrict__ hx, float* __restrict__ out) {
  const int w = threadIdx.x >> 6, lane = threadIdx.x & 63;
  const int b = blockIdx.x * 4 + w;            // one row per wave
  const size_t rb = (size_t)b * N_COLS;

  short8 sxr = *(const short8*)&xt[rb + 8 * lane];
  short8 sxz = *(const short8*)&xt[rb + 512 + 8 * lane];
  short8 sxn = *(const short8*)&xt[rb + 1024 + 8 * lane];
  short8 shr = *(const short8*)&ht[rb + 8 * lane];
  short8 shz = *(const short8*)&ht[rb + 512 + 8 * lane];
  short8 shn = *(const short8*)&ht[rb + 1024 + 8 * lane];

  float vxr[8], vxz[8], vxn[8], vhr[8], vhz[8], vhn[8];
#pragma unroll
  for (int k = 0; k < 8; ++k) {
    vxr[k] = bf2f((unsigned short)sxr[k]);
    vxz[k] = bf2f((unsigned short)sxz[k]);
    vxn[k] = bf2f((unsigned short)sxn[k]);
    vhr[k] = bf2f((unsigned short)shr[k]);
    vhz[k] = bf2f((unsigned short)shz[k]);
    vhn[k] = bf2f((unsigned short)shn[k]);
  }

  float pr[8] = {0.f, 0.f, 0.f, 0.f, 0.f, 0.f, 0.f, 0.f};
#pragma unroll
  for (int k = 0; k < 8; ++k) {
    pr[0] += vxr[k] + vxz[k];
    pr[1] += vxr[k] * vxr[k] + vxz[k] * vxz[k];
    pr[2] += vxn[k];
    pr[3] += vxn[k] * vxn[k];
    pr[4] += vhr[k] + vhz[k];
    pr[5] += vhr[k] * vhr[k] + vhz[k] * vhz[k];
    pr[6] += vhn[k];
    pr[7] += vhn[k] * vhn[k];
  }
#pragma unroll
  for (int msk = 1; msk < 64; msk <<= 1)
#pragma unroll
    for (int k = 0; k < 8; ++k) pr[k] += __shfl_xor(pr[k], msk);

  const float inv2H = 1.f / 1024.f, invH = 1.f / 512.f;
  const float mx0 = pr[0] * inv2H;
  const float ix0 = rsqrtf(pr[1] * inv2H - mx0 * mx0 + 1e-5f);
  const float mx1 = pr[2] * invH;
  const float ix1 = rsqrtf(pr[3] * invH - mx1 * mx1 + 1e-5f);
  const float mh0 = pr[4] * inv2H;
  const float ih0 = rsqrtf(pr[5] * inv2H - mh0 * mh0 + 1e-5f);
  const float mh1 = pr[6] * invH;
  const float ih1 = rsqrtf(pr[7] * invH - mh1 * mh1 + 1e-5f);

  auto calc = [&](float xrv, float xzv, float xnv, float hrv, float hzv,
                  float hnv, float hxs) -> float {
    float ar = (xrv - mx0) * ix0 + (hrv - mh0) * ih0;
    float az = (xzv - mx0) * ix0 + (hzv - mh0) * ih0;
    float r = 1.f / (1.f + __expf(-ar));
    float z = 1.f / (1.f + __expf(-az));
    float arg = (xnv - mx1) * ix1 + r * ((hnv - mh1) * ih1);
    float e2 = __expf(2.f * arg);
    float nn = (e2 - 1.f) / (e2 + 1.f);
    return z * hxs + (1.f - z) * nn;
  };

  const int base4 = 64 * (lane >> 3) + 4 * (lane & 7);
  const float* hxrow = hx + (size_t)b * H_DIM;
  float* orow = out + (size_t)b * H_DIM;

  float4 hx0 = *(const float4*)&hxrow[base4];
  float4 hx1 = *(const float4*)&hxrow[base4 + 32];
  const float* h0p = (const float*)&hx0;
  const float* h1p = (const float*)&hx1;

  float4 r0, r1;
  float* r0p = (float*)&r0;
  float* r1p = (float*)&r1;
#pragma unroll
  for (int k = 0; k < 4; ++k) {
    r0p[k] = calc(vxr[2 * k], vxz[2 * k], vxn[2 * k],
                  vhr[2 * k], vhz[2 * k], vhn[2 * k], h0p[k]);
    r1p[k] = calc(vxr[2 * k + 1], vxz[2 * k + 1], vxn[2 * k + 1],
                  vhr[2 * k + 1], vhz[2 * k + 1], vhn[2 * k + 1], h1p[k]);
  }
  *(float4*)&orow[base4] = r0;
  *(float4*)&orow[base4 + 32] = r1;
}

// ---------------- launch ----------------
// Workspace layout (bytes):            offset        size
//   Wib (bf16,  1536x512)                   0       1572864
//   Whb (bf16,  1536x512)             1572864       1572864
//   xt  (bf16, 16384x1536, permuted)  3145728      50331648
//   ht  (bf16, 16384x1536, permuted) 53477376      50331648
extern "C" void kernel_launch(void* const* d_in, const int* in_sizes, int n_in,
                              void* d_out, int out_size, void* d_ws, size_t ws_size,
                              hipStream_t stream) {
  const float* x  = (const float*)d_in[0];
  const float* hx = (const float*)d_in[1];
  const float* Wi = (const float*)d_in[2];
  const float* bi = (const float*)d_in[3];
  const float* Wh = (const float*)d_in[4];
  const float* bh = (const float*)d_in[5];
  float* out = (float*)d_out;

  char* ws = (char*)d_ws;
  unsigned short* Wib = (unsigned short*)(ws);
  unsigned short* Whb = (unsigned short*)(ws + 1572864);
  unsigned short* xt  = (unsigned short*)(ws + 3145728);
  unsigned short* ht  = (unsigned short*)(ws + 53477376);

  cvt_w<<<1536, 256, 0, stream>>>(Wi, Wh, Wib, Whb);

  gemm_bf16<<<dim3(1536, 1, 2), 256, 0, stream>>>(
      x, hx, Wib, Whb, bi, bh, xt, ht);

  finalize_kernel<<<M_ROWS / 4, 256, 0, stream>>>(xt, ht, hx, out);
}

// Round 4
// 205.126 us; speedup vs baseline: 1.0188x; 1.0188x over previous
//
#include <hip/hip_runtime.h>

// Problem constants: B=16384, D_in=512, H=512
#define M_ROWS 16384
#define N_COLS 1536   // 3*H
#define K_DIM  512
#define H_DIM  512
#define NT     8      // K_DIM / 64 K-tiles

typedef __attribute__((ext_vector_type(8))) short short8;   // 8 bf16 = 4 VGPRs
typedef __attribute__((ext_vector_type(16))) float f32x16;  // 32x32 MFMA acc

__device__ __forceinline__ unsigned short f2bf(float f) {
  unsigned u = __float_as_uint(f);
  u += 0x7fffu + ((u >> 16) & 1u);   // RNE
  return (unsigned short)(u >> 16);
}
__device__ __forceinline__ float bf2f(unsigned short h) {
  return __uint_as_float(((unsigned)h) << 16);
}
__device__ __forceinline__ unsigned cvt_pk_bf16(float lo, float hi) {
  unsigned r;
  asm("v_cvt_pk_bf16_f32 %0, %1, %2" : "=v"(r) : "v"(lo), "v"(hi));  // RNE, lo in [15:0]
  return r;
}

__device__ __forceinline__ void gload_lds16(const void* g, void* l) {
  __builtin_amdgcn_global_load_lds((const __attribute__((address_space(1))) void*)g,
                                   (__attribute__((address_space(3))) void*)l,
                                   16, 0, 0);
}

// ---------------- fp32 -> bf16 convert, W only (9.4 MB pass) ----------------
__global__ __launch_bounds__(256) void cvt_w(
    const float* __restrict__ Wi, const float* __restrict__ Wh,
    unsigned short* __restrict__ Wib, unsigned short* __restrict__ Whb) {
  int i = blockIdx.x * blockDim.x + threadIdx.x;   // grid exactly 393216 threads
  const float* s; unsigned short* d; int off;
  if (i < 196608) { s = Wi; d = Wib; off = i; }
  else            { s = Wh; d = Whb; off = i - 196608; }
  float4 f = ((const float4*)s)[off];
  ushort4 u;
  u.x = f2bf(f.x); u.y = f2bf(f.y); u.z = f2bf(f.z); u.w = f2bf(f.w);
  ((ushort4*)d)[off] = u;
}

// ---------------- GEMM (bf16 MFMA 32x32x16) + bias, permuted store ----------
// C[m][n] = sum_k A[m][k]*W[n][k] + bias[n].  blockIdx.z: 0=(x,Wi,bi,xt) 1=(hx,Wh,bh,ht)
// v5 = r0's proven loop discipline (128x128 tile, 4 waves 2x2, single-buffered
// stage -> sync -> 4xMFMA-phase -> sync, plain grid) with A staged AS FP32 via
// global_load_lds (no separate x/hx conversion pass):
//   A (x/hx fp32): 8 gload_lds16/wave into 32 KB LDS tile [128 rows][64 floats],
//     fp32 chunk swizzle p = j ^ ((r&7)<<1) ^ ((r>>3)&1) pre-applied to the
//     GLOBAL source address (LDS dest linear, per G21).  Fragment read =
//     2x ds_read_b128 + 4x v_cvt_pk_bf16_f32 (hidden under MFMA phase).
//   B (W bf16): r0-identical gload_lds path, chunk swizzle c^(r&7).
// Store permutation within each aligned 64-col group: value for true col
// 32*j + c (c=lane&31, j=0..1) stored at slot 2c+j  -> finalize decode unchanged.
__global__ __launch_bounds__(256, 3) void gemm_bf16(
    const float* __restrict__ x, const float* __restrict__ hx,
    const unsigned short* __restrict__ Wib, const unsigned short* __restrict__ Whb,
    const float* __restrict__ b_i2h, const float* __restrict__ b_h2h,
    unsigned short* __restrict__ xt, unsigned short* __restrict__ ht) {
  const int mat = blockIdx.z;
  const float* A32         = mat ? hx : x;
  const unsigned short* Bw = mat ? Whb : Wib;
  const float* bias        = mat ? b_h2h : b_i2h;
  unsigned short* outp     = mat ? ht : xt;

  const int m0 = blockIdx.x * 128;
  const int n0 = blockIdx.y * 128;

  // ldsA: fp32 [128][64] = 32 KiB.  ldsB: bf16 [128][64] = 16 KiB.  48 KiB.
  __shared__ float ldsA[128 * 64];
  __shared__ short ldsB[128 * 64];

  const int t = threadIdx.x;
  const int w = t >> 6, lane = t & 63;
  const int w_row = w >> 1, w_col = w & 1;
  const int l31 = lane & 31, h = lane >> 5;
  const int srow = lane >> 3;                   // B: 0..7 row within 8-row seg
  const int scol = ((lane & 7) ^ srow) * 8;     // B: XOR pre-swizzled source chunk
  // A read-side swizzle is a per-lane constant: tile row r = w_row*64+i*32+l31
  // has r&7 == l31&7 and (r>>3)&1 == (l31>>3)&1.
  const int swA = ((l31 & 7) << 1) ^ ((l31 >> 3) & 1);

  f32x16 acc[2][2];
#pragma unroll
  for (int i = 0; i < 2; ++i)
#pragma unroll
    for (int j = 0; j < 2; ++j)
#pragma unroll
      for (int r = 0; r < 16; ++r) acc[i][j][r] = 0.f;

  for (int kt = 0; kt < NT; ++kt) {
    const int k0 = kt * 64;
    // ---- A stage: 8 instrs/wave, 4 tile-rows per instr (16 lanes x 16B/row).
    // LDS dest linear: row R+(lane>>4), fp32 chunk lane&15.  Global source
    // supplies logical chunk j = p ^ ((r&7)<<1) ^ ((r>>3)&1).
#pragma unroll
    for (int q = 0; q < 8; ++q) {
      const int R = w * 32 + q * 4;
      const int r = R + (lane >> 4);
      const int j = (lane & 15) ^ ((r & 7) << 1) ^ ((r >> 3) & 1);
      gload_lds16(A32 + (size_t)(m0 + r) * K_DIM + k0 + j * 4, &ldsA[R * 64]);
    }
    // ---- B stage: r0-identical, 4 instrs/wave.
#pragma unroll
    for (int q2 = 0; q2 < 4; ++q2) {
      const int br = w * 32 + q2 * 8;
      gload_lds16(Bw + (size_t)(n0 + br + srow) * K_DIM + k0 + scol, &ldsB[br * 64]);
    }
    __syncthreads();     // drains vmcnt: both tiles resident

#pragma unroll
    for (int kk = 0; kk < 4; ++kk) {
      // A: lane needs floats k = kk*16 + h*8 .. +7  -> logical fp32 chunks
      // j0 = kk*4+2h and j0+1, at physical chunks (j^swA).
      const int j0 = kk * 4 + 2 * h;
      const int p0 = (j0 ^ swA) * 4;
      const int p1 = ((j0 + 1) ^ swA) * 4;
      short8 af[2], bfr[2];
#pragma unroll
      for (int i = 0; i < 2; ++i) {
        const float* rowp = &ldsA[(w_row * 64 + i * 32 + l31) * 64];
        float4 fa0 = *(const float4*)&rowp[p0];
        float4 fa1 = *(const float4*)&rowp[p1];
        union { uint4 u; short8 s; } cv;
        cv.u.x = cvt_pk_bf16(fa0.x, fa0.y);
        cv.u.y = cvt_pk_bf16(fa0.z, fa0.w);
        cv.u.z = cvt_pk_bf16(fa1.x, fa1.y);
        cv.u.w = cvt_pk_bf16(fa1.z, fa1.w);
        af[i] = cv.s;
      }
      // B: bf16 chunk = ((kk*2+h) ^ (row&7)), row&7 == l31&7  (r0-identical)
      const int chunk = ((kk * 2 + h) ^ (l31 & 7)) * 8;
#pragma unroll
      for (int j = 0; j < 2; ++j)
        bfr[j] = *(const short8*)&ldsB[(w_col * 64 + j * 32 + l31) * 64 + chunk];
#pragma unroll
      for (int i = 0; i < 2; ++i)
#pragma unroll
        for (int j = 0; j < 2; ++j)
          acc[i][j] = __builtin_amdgcn_mfma_f32_32x32x16_bf16(af[i], bfr[j], acc[i][j], 0, 0, 0);
    }
    __syncthreads();     // WAR: next stage overwrites both tiles
  }

  // Epilogue: bias + packed permuted ushort2 store.
  // C/D: col=l31, row=(reg&3)+8*(reg>>2)+4*h
  const float biasj0 = bias[n0 + w_col * 64 + l31];
  const float biasj1 = bias[n0 + w_col * 64 + 32 + l31];
#pragma unroll
  for (int i = 0; i < 2; ++i) {
#pragma unroll
    for (int g = 0; g < 4; ++g) {
#pragma unroll
      for (int d = 0; d < 4; ++d) {
        const int reg = g * 4 + d;
        const int row = d + 8 * g + 4 * h;
        ushort2 pk;
        pk.x = f2bf(acc[i][0][reg] + biasj0);
        pk.y = f2bf(acc[i][1][reg] + biasj1);
        *(ushort2*)(outp + (size_t)(m0 + w_row * 64 + i * 32 + row) * N_COLS +
                    n0 + w_col * 64 + 2 * l31) = pk;
      }
    }
  }
}

// ---------------- finalize: wave-per-row, b128 loads, float4 hx/out ---------
// Permuted slot s (within aligned 64-group) holds true col 32*(s&1)+(s>>1).
// hx is read as fp32 directly (exact, no hxb buffer).
__global__ __launch_bounds__(256) void finalize_kernel(
    const unsigned short* __restrict__ xt, const unsigned short* __restrict__ ht,
    const float* __restrict__ hx, float* __restrict__ out) {
  const int w = threadIdx.x >> 6, lane = threadIdx.x & 63;
  const int b = blockIdx.x * 4 + w;            // one row per wave
  const size_t rb = (size_t)b * N_COLS;

  short8 sxr = *(const short8*)&xt[rb + 8 * lane];
  short8 sxz = *(const short8*)&xt[rb + 512 + 8 * lane];
  short8 sxn = *(const short8*)&xt[rb + 1024 + 8 * lane];
  short8 shr = *(const short8*)&ht[rb + 8 * lane];
  short8 shz = *(const short8*)&ht[rb + 512 + 8 * lane];
  short8 shn = *(const short8*)&ht[rb + 1024 + 8 * lane];

  float vxr[8], vxz[8], vxn[8], vhr[8], vhz[8], vhn[8];
#pragma unroll
  for (int k = 0; k < 8; ++k) {
    vxr[k] = bf2f((unsigned short)sxr[k]);
    vxz[k] = bf2f((unsigned short)sxz[k]);
    vxn[k] = bf2f((unsigned short)sxn[k]);
    vhr[k] = bf2f((unsigned short)shr[k]);
    vhz[k] = bf2f((unsigned short)shz[k]);
    vhn[k] = bf2f((unsigned short)shn[k]);
  }

  float pr[8] = {0.f, 0.f, 0.f, 0.f, 0.f, 0.f, 0.f, 0.f};
#pragma unroll
  for (int k = 0; k < 8; ++k) {
    pr[0] += vxr[k] + vxz[k];
    pr[1] += vxr[k] * vxr[k] + vxz[k] * vxz[k];
    pr[2] += vxn[k];
    pr[3] += vxn[k] * vxn[k];
    pr[4] += vhr[k] + vhz[k];
    pr[5] += vhr[k] * vhr[k] + vhz[k] * vhz[k];
    pr[6] += vhn[k];
    pr[7] += vhn[k] * vhn[k];
  }
#pragma unroll
  for (int msk = 1; msk < 64; msk <<= 1)
#pragma unroll
    for (int k = 0; k < 8; ++k) pr[k] += __shfl_xor(pr[k], msk);

  const float inv2H = 1.f / 1024.f, invH = 1.f / 512.f;
  const float mx0 = pr[0] * inv2H;
  const float ix0 = rsqrtf(pr[1] * inv2H - mx0 * mx0 + 1e-5f);
  const float mx1 = pr[2] * invH;
  const float ix1 = rsqrtf(pr[3] * invH - mx1 * mx1 + 1e-5f);
  const float mh0 = pr[4] * inv2H;
  const float ih0 = rsqrtf(pr[5] * inv2H - mh0 * mh0 + 1e-5f);
  const float mh1 = pr[6] * invH;
  const float ih1 = rsqrtf(pr[7] * invH - mh1 * mh1 + 1e-5f);

  auto calc = [&](float xrv, float xzv, float xnv, float hrv, float hzv,
                  float hnv, float hxs) -> float {
    float ar = (xrv - mx0) * ix0 + (hrv - mh0) * ih0;
    float az = (xzv - mx0) * ix0 + (hzv - mh0) * ih0;
    float r = 1.f / (1.f + __expf(-ar));
    float z = 1.f / (1.f + __expf(-az));
    float arg = (xnv - mx1) * ix1 + r * ((hnv - mh1) * ih1);
    float e2 = __expf(2.f * arg);
    float nn = (e2 - 1.f) / (e2 + 1.f);
    return z * hxs + (1.f - z) * nn;
  };

  const int base4 = 64 * (lane >> 3) + 4 * (lane & 7);
  const float* hxrow = hx + (size_t)b * H_DIM;
  float* orow = out + (size_t)b * H_DIM;

  float4 hx0 = *(const float4*)&hxrow[base4];
  float4 hx1 = *(const float4*)&hxrow[base4 + 32];
  const float* h0p = (const float*)&hx0;
  const float* h1p = (const float*)&hx1;

  float4 r0, r1;
  float* r0p = (float*)&r0;
  float* r1p = (float*)&r1;
#pragma unroll
  for (int k = 0; k < 4; ++k) {
    r0p[k] = calc(vxr[2 * k], vxz[2 * k], vxn[2 * k],
                  vhr[2 * k], vhz[2 * k], vhn[2 * k], h0p[k]);
    r1p[k] = calc(vxr[2 * k + 1], vxz[2 * k + 1], vxn[2 * k + 1],
                  vhr[2 * k + 1], vhz[2 * k + 1], vhn[2 * k + 1], h1p[k]);
  }
  *(float4*)&orow[base4] = r0;
  *(float4*)&orow[base4 + 32] = r1;
}

// ---------------- launch ----------------
// Workspace layout (bytes):            offset        size
//   Wib (bf16,  1536x512)                   0       1572864
//   Whb (bf16,  1536x512)             1572864       1572864
//   xt  (bf16, 16384x1536, permuted)  3145728      50331648
//   ht  (bf16, 16384x1536, permuted) 53477376      50331648
extern "C" void kernel_launch(void* const* d_in, const int* in_sizes, int n_in,
                              void* d_out, int out_size, void* d_ws, size_t ws_size,
                              hipStream_t stream) {
  const float* x  = (const float*)d_in[0];
  const float* hx = (const float*)d_in[1];
  const float* Wi = (const float*)d_in[2];
  const float* bi = (const float*)d_in[3];
  const float* Wh = (const float*)d_in[4];
  const float* bh = (const float*)d_in[5];
  float* out = (float*)d_out;

  char* ws = (char*)d_ws;
  unsigned short* Wib = (unsigned short*)(ws);
  unsigned short* Whb = (unsigned short*)(ws + 1572864);
  unsigned short* xt  = (unsigned short*)(ws + 3145728);
  unsigned short* ht  = (unsigned short*)(ws + 53477376);

  cvt_w<<<1536, 256, 0, stream>>>(Wi, Wh, Wib, Whb);

  gemm_bf16<<<dim3(M_ROWS / 128, N_COLS / 128, 2), 256, 0, stream>>>(
      x, hx, Wib, Whb, bi, bh, xt, ht);

  finalize_kernel<<<M_ROWS / 4, 256, 0, stream>>>(xt, ht, hx, out);
}